// Round 17
// baseline (53.431 us; speedup 1.0000x reference)
//
#include <hip/hip_runtime.h>

#define KINST 64

typedef float v2f __attribute__((ext_vector_type(2)));

__device__ __forceinline__ int decode_k0(float t0, float t1, float t2,
                                         const int* pal_s) {
  int pid = (int)(fmaf(t0, 65536.f, fmaf(t1, 256.f, t2)) + 0.5f);
  if (pid >= 0 && pid < KINST && pal_s[pid] == pid) return pid;  // fast path
  for (int j = 0; j < KINST; ++j)
    if (pal_s[j] == pid) return j;
  return KINST;  // no palette match
}

// ---------------------------------------------------------------------------
// Pass 1: per-(b,block) PARTIAL histograms via LDS atomics; plain coalesced
// stores. Block (0,0) zeroes out[0]. partialS: [B][nbs][256], i = c*64+k.
// ---------------------------------------------------------------------------
__global__ __launch_bounds__(256) void k_stats(const float* __restrict__ pred,
                                               const float* __restrict__ targ,
                                               const int* __restrict__ pal,
                                               float* __restrict__ partialS,
                                               unsigned char* __restrict__ k0c,
                                               float* __restrict__ out,
                                               int HW) {
  int b = blockIdx.y;
  __shared__ float ls[4][4][KINST];  // [wave][component][k]
  __shared__ int pal_s[KINST];
  if (blockIdx.x == 0 && blockIdx.y == 0 && threadIdx.x == 0) out[0] = 0.f;
  for (int i = threadIdx.x; i < 4 * 4 * KINST; i += blockDim.x)
    (&ls[0][0][0])[i] = 0.f;
  for (int i = threadIdx.x; i < KINST; i += blockDim.x) pal_s[i] = pal[i];
  __syncthreads();
  int w = threadIdx.x >> 6;
  const float* tb = targ + (size_t)b * 3 * HW;
  const float* pb = pred + (size_t)b * 3 * HW;
  unsigned char* kb = k0c ? k0c + (size_t)b * HW : nullptr;
  int nq = HW >> 2;
  const float4* tb4 = (const float4*)tb;
  const float4* pb4 = (const float4*)pb;
  for (int q = blockIdx.x * blockDim.x + threadIdx.x; q < nq;
       q += gridDim.x * blockDim.x) {
    float4 t0 = tb4[q], t1 = tb4[q + nq], t2 = tb4[q + 2 * nq];
    float4 p0 = pb4[q], p1 = pb4[q + nq], p2 = pb4[q + 2 * nq];
    int ka = decode_k0(t0.x, t1.x, t2.x, pal_s);
    int kc = decode_k0(t0.y, t1.y, t2.y, pal_s);
    int kd = decode_k0(t0.z, t1.z, t2.z, pal_s);
    int ke = decode_k0(t0.w, t1.w, t2.w, pal_s);
    if (ka < KINST) {
      atomicAdd(&ls[w][0][ka], p0.x); atomicAdd(&ls[w][1][ka], p1.x);
      atomicAdd(&ls[w][2][ka], p2.x); atomicAdd(&ls[w][3][ka], 1.f);
    }
    if (kc < KINST) {
      atomicAdd(&ls[w][0][kc], p0.y); atomicAdd(&ls[w][1][kc], p1.y);
      atomicAdd(&ls[w][2][kc], p2.y); atomicAdd(&ls[w][3][kc], 1.f);
    }
    if (kd < KINST) {
      atomicAdd(&ls[w][0][kd], p0.z); atomicAdd(&ls[w][1][kd], p1.z);
      atomicAdd(&ls[w][2][kd], p2.z); atomicAdd(&ls[w][3][kd], 1.f);
    }
    if (ke < KINST) {
      atomicAdd(&ls[w][0][ke], p0.w); atomicAdd(&ls[w][1][ke], p1.w);
      atomicAdd(&ls[w][2][ke], p2.w); atomicAdd(&ls[w][3][ke], 1.f);
    }
    if (kb) {
      uchar4 kk = make_uchar4((unsigned char)ka, (unsigned char)kc,
                              (unsigned char)kd, (unsigned char)ke);
      *(uchar4*)(kb + 4 * (size_t)q) = kk;
    }
  }
  // scalar tail (HW % 4 != 0 only)
  for (int i = (nq << 2) + blockIdx.x * blockDim.x + threadIdx.x; i < HW;
       i += gridDim.x * blockDim.x) {
    int k0 = decode_k0(tb[i], tb[i + HW], tb[i + 2 * HW], pal_s);
    if (kb) kb[i] = (unsigned char)k0;
    if (k0 < KINST) {
      atomicAdd(&ls[w][0][k0], pb[i]); atomicAdd(&ls[w][1][k0], pb[i + HW]);
      atomicAdd(&ls[w][2][k0], pb[i + 2 * HW]); atomicAdd(&ls[w][3][k0], 1.f);
    }
  }
  __syncthreads();
  float* o = partialS + ((size_t)b * gridDim.x + blockIdx.x) * 256;
  int i = threadIdx.x;  // i = c*64+k
  int c = i >> 6, k = i & 63;
  o[i] = ls[0][c][k] + ls[1][c][k] + ls[2][c][k] + ls[3][c][k];
}

// ---------------------------------------------------------------------------
// Shared preamble: reduce partialS[b] (unroll 8, fixed order) into red[256].
// ---------------------------------------------------------------------------
__device__ __forceinline__ float reduce_partials(const float* __restrict__ src,
                                                 int nbs, int i) {
  float s0 = 0.f, s1 = 0.f, s2 = 0.f, s3 = 0.f;
  float s4 = 0.f, s5 = 0.f, s6 = 0.f, s7 = 0.f;
  int bx = 0;
  for (; bx + 8 <= nbs; bx += 8) {
    s0 += src[(size_t)(bx + 0) * 256 + i];
    s1 += src[(size_t)(bx + 1) * 256 + i];
    s2 += src[(size_t)(bx + 2) * 256 + i];
    s3 += src[(size_t)(bx + 3) * 256 + i];
    s4 += src[(size_t)(bx + 4) * 256 + i];
    s5 += src[(size_t)(bx + 5) * 256 + i];
    s6 += src[(size_t)(bx + 6) * 256 + i];
    s7 += src[(size_t)(bx + 7) * 256 + i];
  }
  for (; bx < nbs; ++bx) s0 += src[(size_t)bx * 256 + i];
  return ((s0 + s1) + (s2 + s3)) + ((s4 + s5) + (s6 + s7));
}

// ---------------------------------------------------------------------------
// Pass 2 (hot): pixel loop with IN-KERNEL table build (preamble recomputes
// the partial-reduce + tables per block; deletes the k_reduce dispatch and
// the A/W/Z global roundtrip). 4 px/thread; packed-f32 inner loop; LDS
// uniform-broadcast tables.
// ---------------------------------------------------------------------------
template <bool USE_CACHE>
__global__ __launch_bounds__(256) void k_pix(const float* __restrict__ pred,
                                             const float* __restrict__ targ,
                                             const unsigned char* __restrict__ k0c,
                                             const int* __restrict__ pal,
                                             const float* __restrict__ partialS,
                                             const unsigned char* __restrict__ nb_raw,
                                             const float* __restrict__ dw,
                                             int ndw, int nbs,
                                             float* __restrict__ res_part,
                                             int HW, int B) {
  int b = blockIdx.y;
  __shared__ float red[256];
  __shared__ float scale_sh[KINST];
  __shared__ float4 A_s[KINST + 1];
  __shared__ float4 Z_s[KINST + 1];
  __shared__ float W_s[KINST + 1];
  __shared__ float cwN[KINST][KINST + 1];
  __shared__ int pal_s[KINST];
  __shared__ int nu_sh;
  __shared__ float rA[4], rB[4];
  int t = threadIdx.x;
  // ---- preamble: rebuild tables from partialS (same order as ever) ----
  red[t] = reduce_partials(partialS + (size_t)b * nbs * 256, nbs, t);
  if (t == 0) nu_sh = 0;
  if (!USE_CACHE && t < KINST) pal_s[t] = pal[t];
  __syncthreads();
  {  // dw-uniformity scan (per block; 16 loads/thread of L1-resident dw)
    float d0 = dw[0];
    int nu = 0;
    for (int x = t; x < ndw; x += blockDim.x) nu |= (dw[x] != d0);
    if (nu) atomicOr(&nu_sh, 1);
  }
  __syncthreads();
  if (t < KINST) {
    float m0s = red[t], m1s = red[64 + t], m2s = red[128 + t],
          cnt = red[192 + t];
    float inv = cnt > 0.f ? 1.f / cnt : 0.f;
    float m0 = m0s * inv, m1 = m1s * inv, m2 = m2s * inv;
    bool isbg = (pal[t] == 0);
    bool nb = (nb_raw[b] != 0) || (nb_raw[4 * b] != 0);  // robust bool width
    float cf = (!isbg || !nb) ? 1.f : 0.f;
    float sc = (!isbg && cnt > 0.f) ? 10.f / (((float)HW - cnt) * sqrtf(cnt)) : 0.f;
    A_s[t] = make_float4(-2.f * m0, -2.f * m1, -2.f * m2,
                         m0 * m0 + m1 * m1 + m2 * m2 + 1.f);
    Z_s[t] = make_float4(isbg ? 0.f : m0, isbg ? 0.f : m1, isbg ? 0.f : m2,
                         cnt > 0.f ? cf / (3.f * cnt) : 0.f);
    W_s[t] = 300.f * dw[0] * sc;
    scale_sh[t] = sc;
  }
  if (t == KINST) {
    A_s[KINST] = make_float4(0.f, 0.f, 0.f, 1.f);
    Z_s[KINST] = make_float4(0.f, 0.f, 0.f, 0.f);
    W_s[KINST] = 0.f;
  }
  __syncthreads();
  bool nonuni = nu_sh != 0;
  if (nonuni) {
    for (int i = t; i < KINST * (KINST + 1); i += blockDim.x) {
      int kk = i / (KINST + 1), j = i - kk * (KINST + 1);
      float v = 0.f;
      if (j < KINST && j != kk) v = 300.f * dw[kk * KINST + j] * scale_sh[kk];
      (&cwN[0][0])[i] = v;
    }
    __syncthreads();
  }
  // ---- pixel loop (R15 body) ----
  const float* pb = pred + (size_t)b * 3 * HW;
  const float* tb = targ + (size_t)b * 3 * HW;
  const float4* pb4 = (const float4*)pb;
  const float4* tb4 = (const float4*)tb;
  int nq = HW >> 2;
  const uchar4* kb4 = USE_CACHE ? (const uchar4*)(k0c + (size_t)b * HW) : nullptr;
  float intra_l = 0.f, inter_l = 0.f;
  for (int q = blockIdx.x * blockDim.x + t; q < nq;
       q += gridDim.x * blockDim.x) {
    float4 P0 = pb4[q], P1 = pb4[q + nq], P2 = pb4[q + 2 * nq];
    int ka, kc, kd, ke;
    if (USE_CACHE) {
      uchar4 kk = kb4[q];
      ka = kk.x; kc = kk.y; kd = kk.z; ke = kk.w;
    } else {
      float4 T0 = tb4[q], T1 = tb4[q + nq], T2 = tb4[q + 2 * nq];
      ka = decode_k0(T0.x, T1.x, T2.x, pal_s);
      kc = decode_k0(T0.y, T1.y, T2.y, pal_s);
      kd = decode_k0(T0.z, T1.z, T2.z, pal_s);
      ke = decode_k0(T0.w, T1.w, T2.w, pal_s);
    }
    float ppa = fmaf(P0.x, P0.x, fmaf(P1.x, P1.x, P2.x * P2.x));
    float ppb = fmaf(P0.y, P0.y, fmaf(P1.y, P1.y, P2.y * P2.y));
    float ppc = fmaf(P0.z, P0.z, fmaf(P1.z, P1.z, P2.z * P2.z));
    float ppd = fmaf(P0.w, P0.w, fmaf(P1.w, P1.w, P2.w * P2.w));
    float aa = 0.f, ab = 0.f, ac = 0.f, ad = 0.f;
    if (!nonuni) {
      v2f pp01 = {ppa, ppb}, pp23 = {ppc, ppd};
      v2f P0a = {P0.x, P0.y}, P0b = {P0.z, P0.w};
      v2f P1a = {P1.x, P1.y}, P1b = {P1.z, P1.w};
      v2f P2a = {P2.x, P2.y}, P2b = {P2.z, P2.w};
      v2f acc01 = {0.f, 0.f}, acc23 = {0.f, 0.f};
      #pragma unroll 8
      for (int k = 0; k < KINST; ++k) {
        float4 a = A_s[k];          // uniform addr -> broadcast b128
        float wv = W_s[k];          // uniform addr -> broadcast b32
        v2f ax = {a.x, a.x}, ay = {a.y, a.y}, az = {a.z, a.z}, aw = {a.w, a.w};
        v2f wv2 = {wv, wv};
        v2f t01 = __builtin_elementwise_fma(P0a, ax, aw);
        t01 = __builtin_elementwise_fma(P1a, ay, t01);
        t01 = __builtin_elementwise_fma(P2a, az, t01);
        v2f arg01 = pp01 + t01;
        v2f t23 = __builtin_elementwise_fma(P0b, ax, aw);
        t23 = __builtin_elementwise_fma(P1b, ay, t23);
        t23 = __builtin_elementwise_fma(P2b, az, t23);
        v2f arg23 = pp23 + t23;
        v2f r01 = {__builtin_amdgcn_rcpf(arg01.x), __builtin_amdgcn_rcpf(arg01.y)};
        v2f r23 = {__builtin_amdgcn_rcpf(arg23.x), __builtin_amdgcn_rcpf(arg23.y)};
        acc01 = __builtin_elementwise_fma(r01, wv2, acc01);
        acc23 = __builtin_elementwise_fma(r23, wv2, acc23);
      }
      aa = acc01.x; ab = acc01.y; ac = acc23.x; ad = acc23.y;
      // diagonal (k==k0) subtract + invalid-pixel mask (LDS gathers)
      {
        float4 a = A_s[ka]; float wv = W_s[ka];
        float r = __builtin_amdgcn_rcpf(
            ppa + fmaf(P0.x, a.x, fmaf(P1.x, a.y, fmaf(P2.x, a.z, a.w))));
        aa = (ka < KINST) ? aa - wv * r : 0.f;
      }
      {
        float4 a = A_s[kc]; float wv = W_s[kc];
        float r = __builtin_amdgcn_rcpf(
            ppb + fmaf(P0.y, a.x, fmaf(P1.y, a.y, fmaf(P2.y, a.z, a.w))));
        ab = (kc < KINST) ? ab - wv * r : 0.f;
      }
      {
        float4 a = A_s[kd]; float wv = W_s[kd];
        float r = __builtin_amdgcn_rcpf(
            ppc + fmaf(P0.z, a.x, fmaf(P1.z, a.y, fmaf(P2.z, a.z, a.w))));
        ac = (kd < KINST) ? ac - wv * r : 0.f;
      }
      {
        float4 a = A_s[ke]; float wv = W_s[ke];
        float r = __builtin_amdgcn_rcpf(
            ppd + fmaf(P0.w, a.x, fmaf(P1.w, a.y, fmaf(P2.w, a.z, a.w))));
        ad = (ke < KINST) ? ad - wv * r : 0.f;
      }
    } else {
      #pragma unroll 4
      for (int k = 0; k < KINST; ++k) {
        float4 a = A_s[k];
        float ra = __builtin_amdgcn_rcpf(
            ppa + fmaf(P0.x, a.x, fmaf(P1.x, a.y, fmaf(P2.x, a.z, a.w))));
        float rb = __builtin_amdgcn_rcpf(
            ppb + fmaf(P0.y, a.x, fmaf(P1.y, a.y, fmaf(P2.y, a.z, a.w))));
        float rc = __builtin_amdgcn_rcpf(
            ppc + fmaf(P0.z, a.x, fmaf(P1.z, a.y, fmaf(P2.z, a.z, a.w))));
        float rd = __builtin_amdgcn_rcpf(
            ppd + fmaf(P0.w, a.x, fmaf(P1.w, a.y, fmaf(P2.w, a.z, a.w))));
        aa = fmaf(ra, cwN[k][ka], aa); ab = fmaf(rb, cwN[k][kc], ab);
        ac = fmaf(rc, cwN[k][kd], ac); ad = fmaf(rd, cwN[k][ke], ad);
      }
    }
    inter_l += (aa + ab) + (ac + ad);
    // intra: huber toward own bg-zeroed mean; f_intra folds cf/(3*cnt)
    {
      float4 z = Z_s[ka];
      float q0 = fabsf(P0.x - z.x), q1 = fabsf(P1.x - z.y), q2 = fabsf(P2.x - z.z);
      float hp = (q0 < 1.f ? 0.5f * q0 * q0 : q0 - 0.5f) +
                 (q1 < 1.f ? 0.5f * q1 * q1 : q1 - 0.5f) +
                 (q2 < 1.f ? 0.5f * q2 * q2 : q2 - 0.5f);
      intra_l = fmaf(hp, z.w, intra_l);
    }
    {
      float4 z = Z_s[kc];
      float q0 = fabsf(P0.y - z.x), q1 = fabsf(P1.y - z.y), q2 = fabsf(P2.y - z.z);
      float hp = (q0 < 1.f ? 0.5f * q0 * q0 : q0 - 0.5f) +
                 (q1 < 1.f ? 0.5f * q1 * q1 : q1 - 0.5f) +
                 (q2 < 1.f ? 0.5f * q2 * q2 : q2 - 0.5f);
      intra_l = fmaf(hp, z.w, intra_l);
    }
    {
      float4 z = Z_s[kd];
      float q0 = fabsf(P0.z - z.x), q1 = fabsf(P1.z - z.y), q2 = fabsf(P2.z - z.z);
      float hp = (q0 < 1.f ? 0.5f * q0 * q0 : q0 - 0.5f) +
                 (q1 < 1.f ? 0.5f * q1 * q1 : q1 - 0.5f) +
                 (q2 < 1.f ? 0.5f * q2 * q2 : q2 - 0.5f);
      intra_l = fmaf(hp, z.w, intra_l);
    }
    {
      float4 z = Z_s[ke];
      float q0 = fabsf(P0.w - z.x), q1 = fabsf(P1.w - z.y), q2 = fabsf(P2.w - z.z);
      float hp = (q0 < 1.f ? 0.5f * q0 * q0 : q0 - 0.5f) +
                 (q1 < 1.f ? 0.5f * q1 * q1 : q1 - 0.5f) +
                 (q2 < 1.f ? 0.5f * q2 * q2 : q2 - 0.5f);
      intra_l = fmaf(hp, z.w, intra_l);
    }
  }
  // scalar tail pixels (HW % 4 != 0 only)
  for (int i = (nq << 2) + blockIdx.x * blockDim.x + t; i < HW;
       i += gridDim.x * blockDim.x) {
    float p0 = pb[i], p1 = pb[i + HW], p2 = pb[i + 2 * HW];
    int k0 = USE_CACHE ? (int)k0c[(size_t)b * HW + i]
                       : decode_k0(tb[i], tb[i + HW], tb[i + 2 * HW], pal_s);
    float pp = fmaf(p0, p0, fmaf(p1, p1, p2 * p2));
    float acc = 0.f;
    for (int k = 0; k < KINST; ++k) {
      float4 a = A_s[k];
      float r = __builtin_amdgcn_rcpf(
          pp + fmaf(p0, a.x, fmaf(p1, a.y, fmaf(p2, a.z, a.w))));
      float c = nonuni ? cwN[k][k0]
                       : ((k == k0 || k0 >= KINST) ? 0.f : W_s[k]);
      acc = fmaf(r, c, acc);
    }
    inter_l += acc;
    float4 z = Z_s[k0];
    float q0 = fabsf(p0 - z.x), q1 = fabsf(p1 - z.y), q2 = fabsf(p2 - z.z);
    float hp = (q0 < 1.f ? 0.5f * q0 * q0 : q0 - 0.5f) +
               (q1 < 1.f ? 0.5f * q1 * q1 : q1 - 0.5f) +
               (q2 < 1.f ? 0.5f * q2 * q2 : q2 - 0.5f);
    intra_l = fmaf(hp, z.w, intra_l);
  }
  for (int o = 32; o > 0; o >>= 1) {
    intra_l += __shfl_down(intra_l, o, 64);
    inter_l += __shfl_down(inter_l, o, 64);
  }
  int wid = t >> 6;
  if ((t & 63) == 0) { rA[wid] = intra_l; rB[wid] = inter_l; }
  __syncthreads();
  if (t == 0) {
    float a = 0.f, c = 0.f;
    for (int i = 0; i < 4; ++i) { a += rA[i]; c += rB[i]; }
    float* rp = res_part + ((size_t)b * gridDim.x + blockIdx.x) * 2;
    rp[0] = a; rp[1] = c;  // plain store, no atomics
  }
}

// ---------------------------------------------------------------------------
// Pass 3 (grid=B): recompute zf/msep from partialS (same fixed order as the
// k_pix preamble -> bit-identical), reduce res_part, combine; atomicAdd.
// ---------------------------------------------------------------------------
__global__ __launch_bounds__(256) void k_final(const float* __restrict__ partialS,
                                               const int* __restrict__ pal,
                                               const unsigned char* __restrict__ nb_raw,
                                               const float* __restrict__ dw,
                                               const float* __restrict__ res_part,
                                               int nbs, int ngx,
                                               float* __restrict__ out, int B) {
  int b = blockIdx.x;
  int t = threadIdx.x;
  __shared__ float red[256];
  __shared__ float4 zf[KINST];
  __shared__ float rA[4], rB[4], rC[4], rD[4], rE[4];
  red[t] = reduce_partials(partialS + (size_t)b * nbs * 256, nbs, t);
  __syncthreads();
  if (t < KINST) {
    float m0s = red[t], m1s = red[64 + t], m2s = red[128 + t],
          cnt = red[192 + t];
    float inv = cnt > 0.f ? 1.f / cnt : 0.f;
    bool isbg = (pal[t] == 0);
    bool nb = (nb_raw[b] != 0) || (nb_raw[4 * b] != 0);
    float cf = (!isbg || !nb) ? 1.f : 0.f;
    zf[t] = make_float4(isbg ? 0.f : m0s * inv, isbg ? 0.f : m1s * inv,
                        isbg ? 0.f : m2s * inv, cf);
  }
  __syncthreads();
  float psum = 0.f, pcnt = 0.f, cfs = 0.f, ra = 0.f, rc = 0.f;
  for (int idx = t; idx < KINST * KINST; idx += blockDim.x) {
    int j = idx >> 6, k = idx & 63;
    if (j < k) {
      float4 a = zf[j], c4 = zf[k];
      float m = a.w * c4.w;
      float d0 = a.x - c4.x, d1 = a.y - c4.y, d2 = a.z - c4.z;
      float sqd = d0 * d0 + d1 * d1 + d2 * d2;
      psum += dw[j * KINST + k] * 300.f / (sqd + 1.f) * m;
      pcnt += m;
    }
  }
  if (t < KINST) cfs = zf[t].w;
  for (int bx = t; bx < ngx; bx += blockDim.x) {
    const float* rp = res_part + ((size_t)b * ngx + bx) * 2;
    ra += rp[0]; rc += rp[1];
  }
  for (int o = 32; o > 0; o >>= 1) {
    psum += __shfl_down(psum, o, 64);
    pcnt += __shfl_down(pcnt, o, 64);
    cfs += __shfl_down(cfs, o, 64);
    ra += __shfl_down(ra, o, 64);
    rc += __shfl_down(rc, o, 64);
  }
  int wid = t >> 6;
  if ((t & 63) == 0) {
    rA[wid] = psum; rB[wid] = pcnt; rC[wid] = cfs; rD[wid] = ra; rE[wid] = rc;
  }
  __syncthreads();
  if (t == 0) {
    float ps = 0.f, pc = 0.f, cs = 0.f, sa = 0.f, sc2 = 0.f;
    for (int i = 0; i < 4; ++i) {
      ps += rA[i]; pc += rB[i]; cs += rC[i]; sa += rD[i]; sc2 += rE[i];
    }
    float mean_sep = pc > 0.f ? ps / fmaxf(pc, 1.f) : 0.f;
    float ct = fmaxf(cs, 1.f);
    atomicAdd(out, ((sa + sc2 + mean_sep) / ct) / (float)B);
  }
}

extern "C" void kernel_launch(void* const* d_in, const int* in_sizes, int n_in,
                              void* d_out, int out_size, void* d_ws, size_t ws_size,
                              hipStream_t stream) {
  const float* pred = (const float*)d_in[0];
  const float* targ = (const float*)d_in[1];
  const unsigned char* nb = (const unsigned char*)d_in[2];
  const float* dw = (const float*)d_in[3];
  const int* pal = (const int*)d_in[4];
  int B = in_sizes[2];                 // 4
  int ndw = in_sizes[3];               // K*K = 4096
  int HW = in_sizes[0] / (3 * B);      // 262144  (kernels assume K==64)
  const int GX = 256;                  // k_pix blocks per b

  // ws layout (floats): partialS[B*nbs*256] | res_part[B*GX*2]
  //   ; then bytes: k0c[B*HW]
  auto floats_needed = [&](int nbs) -> size_t {
    return (size_t)B * nbs * 256 + (size_t)B * GX * 2;
  };
  int nbs = 64;
  bool use_cache = true;
  if (ws_size < floats_needed(64) * 4 + (size_t)B * HW) {
    if (ws_size >= floats_needed(32) * 4 + (size_t)B * HW) nbs = 32;
    else { nbs = 32; use_cache = false; }
  }
  float* partialS = (float*)d_ws;
  float* res_part = partialS + (size_t)B * nbs * 256;
  unsigned char* k0c = use_cache ? (unsigned char*)(res_part + (size_t)B * GX * 2)
                                 : nullptr;

  k_stats<<<dim3(nbs, B), 256, 0, stream>>>(pred, targ, pal, partialS, k0c,
                                            (float*)d_out, HW);
  if (use_cache)
    k_pix<true><<<dim3(GX, B), 256, 0, stream>>>(pred, targ, k0c, pal, partialS,
                                                 nb, dw, ndw, nbs, res_part,
                                                 HW, B);
  else
    k_pix<false><<<dim3(GX, B), 256, 0, stream>>>(pred, targ, k0c, pal, partialS,
                                                  nb, dw, ndw, nbs, res_part,
                                                  HW, B);
  k_final<<<B, 256, 0, stream>>>(partialS, pal, nb, dw, res_part, nbs, GX,
                                 (float*)d_out, B);
}

// Round 18
// 52.728 us; speedup vs baseline: 1.0133x; 1.0133x over previous
//
#include <hip/hip_runtime.h>

#define KINST 64

typedef float v2f __attribute__((ext_vector_type(2)));

__device__ __forceinline__ int decode_k0(float t0, float t1, float t2,
                                         const int* pal_s) {
  int pid = (int)(fmaf(t0, 65536.f, fmaf(t1, 256.f, t2)) + 0.5f);
  if (pid >= 0 && pid < KINST && pal_s[pid] == pid) return pid;  // fast path
  for (int j = 0; j < KINST; ++j)
    if (pal_s[j] == pid) return j;
  return KINST;  // no palette match
}

// ---------------------------------------------------------------------------
// Pass 1: per-(b,block) PARTIAL histograms via LDS atomics; plain coalesced
// stores. Block (0,0) zeroes out[0]. partialS: [B][nbs][256], i = c*64+k.
// ---------------------------------------------------------------------------
__global__ __launch_bounds__(256) void k_stats(const float* __restrict__ pred,
                                               const float* __restrict__ targ,
                                               const int* __restrict__ pal,
                                               float* __restrict__ partialS,
                                               unsigned char* __restrict__ k0c,
                                               float* __restrict__ out,
                                               int HW) {
  int b = blockIdx.y;
  __shared__ float ls[4][4][KINST];  // [wave][component][k]
  __shared__ int pal_s[KINST];
  if (blockIdx.x == 0 && blockIdx.y == 0 && threadIdx.x == 0) out[0] = 0.f;
  for (int i = threadIdx.x; i < 4 * 4 * KINST; i += blockDim.x)
    (&ls[0][0][0])[i] = 0.f;
  for (int i = threadIdx.x; i < KINST; i += blockDim.x) pal_s[i] = pal[i];
  __syncthreads();
  int w = threadIdx.x >> 6;
  const float* tb = targ + (size_t)b * 3 * HW;
  const float* pb = pred + (size_t)b * 3 * HW;
  unsigned char* kb = k0c ? k0c + (size_t)b * HW : nullptr;
  int nq = HW >> 2;
  const float4* tb4 = (const float4*)tb;
  const float4* pb4 = (const float4*)pb;
  for (int q = blockIdx.x * blockDim.x + threadIdx.x; q < nq;
       q += gridDim.x * blockDim.x) {
    float4 t0 = tb4[q], t1 = tb4[q + nq], t2 = tb4[q + 2 * nq];
    float4 p0 = pb4[q], p1 = pb4[q + nq], p2 = pb4[q + 2 * nq];
    int ka = decode_k0(t0.x, t1.x, t2.x, pal_s);
    int kc = decode_k0(t0.y, t1.y, t2.y, pal_s);
    int kd = decode_k0(t0.z, t1.z, t2.z, pal_s);
    int ke = decode_k0(t0.w, t1.w, t2.w, pal_s);
    if (ka < KINST) {
      atomicAdd(&ls[w][0][ka], p0.x); atomicAdd(&ls[w][1][ka], p1.x);
      atomicAdd(&ls[w][2][ka], p2.x); atomicAdd(&ls[w][3][ka], 1.f);
    }
    if (kc < KINST) {
      atomicAdd(&ls[w][0][kc], p0.y); atomicAdd(&ls[w][1][kc], p1.y);
      atomicAdd(&ls[w][2][kc], p2.y); atomicAdd(&ls[w][3][kc], 1.f);
    }
    if (kd < KINST) {
      atomicAdd(&ls[w][0][kd], p0.z); atomicAdd(&ls[w][1][kd], p1.z);
      atomicAdd(&ls[w][2][kd], p2.z); atomicAdd(&ls[w][3][kd], 1.f);
    }
    if (ke < KINST) {
      atomicAdd(&ls[w][0][ke], p0.w); atomicAdd(&ls[w][1][ke], p1.w);
      atomicAdd(&ls[w][2][ke], p2.w); atomicAdd(&ls[w][3][ke], 1.f);
    }
    if (kb) {
      uchar4 kk = make_uchar4((unsigned char)ka, (unsigned char)kc,
                              (unsigned char)kd, (unsigned char)ke);
      *(uchar4*)(kb + 4 * (size_t)q) = kk;
    }
  }
  // scalar tail (HW % 4 != 0 only)
  for (int i = (nq << 2) + blockIdx.x * blockDim.x + threadIdx.x; i < HW;
       i += gridDim.x * blockDim.x) {
    int k0 = decode_k0(tb[i], tb[i + HW], tb[i + 2 * HW], pal_s);
    if (kb) kb[i] = (unsigned char)k0;
    if (k0 < KINST) {
      atomicAdd(&ls[w][0][k0], pb[i]); atomicAdd(&ls[w][1][k0], pb[i + HW]);
      atomicAdd(&ls[w][2][k0], pb[i + 2 * HW]); atomicAdd(&ls[w][3][k0], 1.f);
    }
  }
  __syncthreads();
  float* o = partialS + ((size_t)b * gridDim.x + blockIdx.x) * 256;
  int i = threadIdx.x;  // i = c*64+k
  int c = i >> 6, k = i & 63;
  o[i] = ls[0][c][k] + ls[1][c][k] + ls[2][c][k] + ls[3][c][k];
}

// ---------------------------------------------------------------------------
// Pass 2 (grid=B): reduce partials (unroll 8) -> per-(b,k) tables + K^2
// pairwise mean-repulsion. msep_g[b] = {mean_sep, ct}.
// ---------------------------------------------------------------------------
__global__ __launch_bounds__(256) void k_reduce(const float* __restrict__ partialS,
                                                const float* __restrict__ dw,
                                                const int* __restrict__ pal,
                                                const unsigned char* __restrict__ nb_raw,
                                                int ndw, int nbs,
                                                float4* __restrict__ A_g,
                                                float* __restrict__ W_g,
                                                float4* __restrict__ Z_g,
                                                float* __restrict__ cw_g,
                                                int* __restrict__ flagp,
                                                float2* __restrict__ msep_g,
                                                int B, int HW) {
  int b = blockIdx.x;
  int i = threadIdx.x;
  __shared__ float red[256];
  __shared__ float scale_sh[KINST];
  __shared__ float4 zf[KINST];  // {mz0,mz1,mz2, cf}
  __shared__ float rA[4], rB[4], rC[4];
  __shared__ int nu_sh;
  const float* src = partialS + (size_t)b * nbs * 256;
  float s0 = 0.f, s1 = 0.f, s2 = 0.f, s3 = 0.f;
  float s4 = 0.f, s5 = 0.f, s6 = 0.f, s7 = 0.f;
  int bx = 0;
  for (; bx + 8 <= nbs; bx += 8) {
    s0 += src[(size_t)(bx + 0) * 256 + i];
    s1 += src[(size_t)(bx + 1) * 256 + i];
    s2 += src[(size_t)(bx + 2) * 256 + i];
    s3 += src[(size_t)(bx + 3) * 256 + i];
    s4 += src[(size_t)(bx + 4) * 256 + i];
    s5 += src[(size_t)(bx + 5) * 256 + i];
    s6 += src[(size_t)(bx + 6) * 256 + i];
    s7 += src[(size_t)(bx + 7) * 256 + i];
  }
  for (; bx < nbs; ++bx) s0 += src[(size_t)bx * 256 + i];
  float acc = ((s0 + s1) + (s2 + s3)) + ((s4 + s5) + (s6 + s7));
  red[i] = acc;
  if (i == 0) nu_sh = 0;
  __syncthreads();
  {  // dw-uniformity scan, chunked across the B blocks
    int per = (ndw + B - 1) / B;
    int lo = b * per, hi = min(lo + per, ndw);
    float d0 = dw[0];
    int nu = 0;
    for (int x = lo + i; x < hi; x += blockDim.x) nu |= (dw[x] != d0);
    if (nu) atomicOr(&nu_sh, 1);
  }
  __syncthreads();
  if (i < KINST) {
    float m0s = red[i], m1s = red[64 + i], m2s = red[128 + i], cnt = red[192 + i];
    float inv = cnt > 0.f ? 1.f / cnt : 0.f;
    float m0 = m0s * inv, m1 = m1s * inv, m2 = m2s * inv;
    bool isbg = (pal[i] == 0);
    bool nb = (nb_raw[b] != 0) || (nb_raw[4 * b] != 0);  // robust bool width
    float cf = (!isbg || !nb) ? 1.f : 0.f;
    float sc = (!isbg && cnt > 0.f) ? 10.f / (((float)HW - cnt) * sqrtf(cnt)) : 0.f;
    A_g[b * 65 + i] = make_float4(-2.f * m0, -2.f * m1, -2.f * m2,
                                  m0 * m0 + m1 * m1 + m2 * m2 + 1.f);
    Z_g[b * 65 + i] = make_float4(isbg ? 0.f : m0, isbg ? 0.f : m1,
                                  isbg ? 0.f : m2,
                                  cnt > 0.f ? cf / (3.f * cnt) : 0.f);
    W_g[b * 65 + i] = 300.f * dw[0] * sc;
    scale_sh[i] = sc;
    zf[i] = make_float4(isbg ? 0.f : m0, isbg ? 0.f : m1, isbg ? 0.f : m2, cf);
  }
  if (i == KINST) {
    A_g[b * 65 + KINST] = make_float4(0.f, 0.f, 0.f, 1.f);
    Z_g[b * 65 + KINST] = make_float4(0.f, 0.f, 0.f, 0.f);
    W_g[b * 65 + KINST] = 0.f;
  }
  __syncthreads();
  if (i == 0) flagp[b] = nu_sh;
  if (nu_sh) {
    float* ct = cw_g + (size_t)b * KINST * 65;
    for (int t2 = i; t2 < KINST * 65; t2 += blockDim.x) {
      int kk = t2 / 65, j = t2 - kk * 65;
      float v = 0.f;
      if (j < KINST && j != kk) v = 300.f * dw[kk * KINST + j] * scale_sh[kk];
      ct[t2] = v;
    }
  }
  // K^2 pairwise mean repulsion (same fixed order)
  float psum = 0.f, pcnt = 0.f, cfs = 0.f;
  for (int idx = i; idx < KINST * KINST; idx += blockDim.x) {
    int j = idx >> 6, k = idx & 63;
    if (j < k) {
      float4 a = zf[j], c4 = zf[k];
      float m = a.w * c4.w;
      float d0 = a.x - c4.x, d1 = a.y - c4.y, d2 = a.z - c4.z;
      float sqd = d0 * d0 + d1 * d1 + d2 * d2;
      psum += dw[j * KINST + k] * 300.f / (sqd + 1.f) * m;
      pcnt += m;
    }
  }
  if (i < KINST) cfs = zf[i].w;
  for (int o = 32; o > 0; o >>= 1) {
    psum += __shfl_down(psum, o, 64);
    pcnt += __shfl_down(pcnt, o, 64);
    cfs += __shfl_down(cfs, o, 64);
  }
  int wid = i >> 6;
  if ((i & 63) == 0) { rA[wid] = psum; rB[wid] = pcnt; rC[wid] = cfs; }
  __syncthreads();
  if (i == 0) {
    float ps = 0.f, pc = 0.f, cs = 0.f;
    for (int x = 0; x < 4; ++x) { ps += rA[x]; pc += rB[x]; cs += rC[x]; }
    float mean_sep = pc > 0.f ? ps / fmaxf(pc, 1.f) : 0.f;
    msep_g[b] = make_float2(mean_sep, fmaxf(cs, 1.f));
  }
}

// ---------------------------------------------------------------------------
// Pass 3 (hot): pixel-per-lane, 4 px/thread; packed-f32 inner loop; LDS
// uniform-broadcast tables. res_part: [B][gx][2], plain stores.
// ---------------------------------------------------------------------------
template <bool USE_CACHE>
__global__ __launch_bounds__(256) void k_pix(const float* __restrict__ pred,
                                             const float* __restrict__ targ,
                                             const unsigned char* __restrict__ k0c,
                                             const int* __restrict__ pal,
                                             const float4* __restrict__ A_g,
                                             const float* __restrict__ W_g,
                                             const float4* __restrict__ Z_g,
                                             const float* __restrict__ cw_g,
                                             const int* __restrict__ flagp,
                                             float* __restrict__ res_part,
                                             int HW, int B) {
  int b = blockIdx.y;
  __shared__ float4 A_s[KINST + 1];
  __shared__ float4 Z_s[KINST + 1];
  __shared__ float W_s[KINST + 1];
  __shared__ float cwN[KINST][KINST + 1];
  __shared__ int pal_s[KINST];
  __shared__ int nonuni_s;
  __shared__ float rA[4], rB[4];
  int t = threadIdx.x;
  if (t < KINST + 1) {
    A_s[t] = A_g[b * 65 + t];
    Z_s[t] = Z_g[b * 65 + t];
    W_s[t] = W_g[b * 65 + t];
  }
  if (!USE_CACHE && t < KINST) pal_s[t] = pal[t];
  if (t == 0) {
    int f = 0;
    for (int bb = 0; bb < B; ++bb) f |= flagp[bb];
    nonuni_s = f;
  }
  __syncthreads();
  bool nonuni = nonuni_s != 0;
  if (nonuni) {
    const float* cwb = cw_g + (size_t)b * KINST * 65;
    for (int i = t; i < KINST * 65; i += blockDim.x) (&cwN[0][0])[i] = cwb[i];
    __syncthreads();
  }
  const float* pb = pred + (size_t)b * 3 * HW;
  const float* tb = targ + (size_t)b * 3 * HW;
  const float4* pb4 = (const float4*)pb;
  const float4* tb4 = (const float4*)tb;
  int nq = HW >> 2;
  const uchar4* kb4 = USE_CACHE ? (const uchar4*)(k0c + (size_t)b * HW) : nullptr;
  float intra_l = 0.f, inter_l = 0.f;
  for (int q = blockIdx.x * blockDim.x + t; q < nq;
       q += gridDim.x * blockDim.x) {
    float4 P0 = pb4[q], P1 = pb4[q + nq], P2 = pb4[q + 2 * nq];
    int ka, kc, kd, ke;
    if (USE_CACHE) {
      uchar4 kk = kb4[q];
      ka = kk.x; kc = kk.y; kd = kk.z; ke = kk.w;
    } else {
      float4 T0 = tb4[q], T1 = tb4[q + nq], T2 = tb4[q + 2 * nq];
      ka = decode_k0(T0.x, T1.x, T2.x, pal_s);
      kc = decode_k0(T0.y, T1.y, T2.y, pal_s);
      kd = decode_k0(T0.z, T1.z, T2.z, pal_s);
      ke = decode_k0(T0.w, T1.w, T2.w, pal_s);
    }
    float ppa = fmaf(P0.x, P0.x, fmaf(P1.x, P1.x, P2.x * P2.x));
    float ppb = fmaf(P0.y, P0.y, fmaf(P1.y, P1.y, P2.y * P2.y));
    float ppc = fmaf(P0.z, P0.z, fmaf(P1.z, P1.z, P2.z * P2.z));
    float ppd = fmaf(P0.w, P0.w, fmaf(P1.w, P1.w, P2.w * P2.w));
    float aa = 0.f, ab = 0.f, ac = 0.f, ad = 0.f;
    if (!nonuni) {
      v2f pp01 = {ppa, ppb}, pp23 = {ppc, ppd};
      v2f P0a = {P0.x, P0.y}, P0b = {P0.z, P0.w};
      v2f P1a = {P1.x, P1.y}, P1b = {P1.z, P1.w};
      v2f P2a = {P2.x, P2.y}, P2b = {P2.z, P2.w};
      v2f acc01 = {0.f, 0.f}, acc23 = {0.f, 0.f};
      #pragma unroll 8
      for (int k = 0; k < KINST; ++k) {
        float4 a = A_s[k];          // uniform addr -> broadcast b128
        float wv = W_s[k];          // uniform addr -> broadcast b32
        v2f ax = {a.x, a.x}, ay = {a.y, a.y}, az = {a.z, a.z}, aw = {a.w, a.w};
        v2f wv2 = {wv, wv};
        v2f t01 = __builtin_elementwise_fma(P0a, ax, aw);
        t01 = __builtin_elementwise_fma(P1a, ay, t01);
        t01 = __builtin_elementwise_fma(P2a, az, t01);
        v2f arg01 = pp01 + t01;
        v2f t23 = __builtin_elementwise_fma(P0b, ax, aw);
        t23 = __builtin_elementwise_fma(P1b, ay, t23);
        t23 = __builtin_elementwise_fma(P2b, az, t23);
        v2f arg23 = pp23 + t23;
        v2f r01 = {__builtin_amdgcn_rcpf(arg01.x), __builtin_amdgcn_rcpf(arg01.y)};
        v2f r23 = {__builtin_amdgcn_rcpf(arg23.x), __builtin_amdgcn_rcpf(arg23.y)};
        acc01 = __builtin_elementwise_fma(r01, wv2, acc01);
        acc23 = __builtin_elementwise_fma(r23, wv2, acc23);
      }
      aa = acc01.x; ab = acc01.y; ac = acc23.x; ad = acc23.y;
      // diagonal (k==k0) subtract + invalid-pixel mask (LDS gathers)
      {
        float4 a = A_s[ka]; float wv = W_s[ka];
        float r = __builtin_amdgcn_rcpf(
            ppa + fmaf(P0.x, a.x, fmaf(P1.x, a.y, fmaf(P2.x, a.z, a.w))));
        aa = (ka < KINST) ? aa - wv * r : 0.f;
      }
      {
        float4 a = A_s[kc]; float wv = W_s[kc];
        float r = __builtin_amdgcn_rcpf(
            ppb + fmaf(P0.y, a.x, fmaf(P1.y, a.y, fmaf(P2.y, a.z, a.w))));
        ab = (kc < KINST) ? ab - wv * r : 0.f;
      }
      {
        float4 a = A_s[kd]; float wv = W_s[kd];
        float r = __builtin_amdgcn_rcpf(
            ppc + fmaf(P0.z, a.x, fmaf(P1.z, a.y, fmaf(P2.z, a.z, a.w))));
        ac = (kd < KINST) ? ac - wv * r : 0.f;
      }
      {
        float4 a = A_s[ke]; float wv = W_s[ke];
        float r = __builtin_amdgcn_rcpf(
            ppd + fmaf(P0.w, a.x, fmaf(P1.w, a.y, fmaf(P2.w, a.z, a.w))));
        ad = (ke < KINST) ? ad - wv * r : 0.f;
      }
    } else {
      #pragma unroll 4
      for (int k = 0; k < KINST; ++k) {
        float4 a = A_s[k];
        float ra = __builtin_amdgcn_rcpf(
            ppa + fmaf(P0.x, a.x, fmaf(P1.x, a.y, fmaf(P2.x, a.z, a.w))));
        float rb = __builtin_amdgcn_rcpf(
            ppb + fmaf(P0.y, a.x, fmaf(P1.y, a.y, fmaf(P2.y, a.z, a.w))));
        float rc = __builtin_amdgcn_rcpf(
            ppc + fmaf(P0.z, a.x, fmaf(P1.z, a.y, fmaf(P2.z, a.z, a.w))));
        float rd = __builtin_amdgcn_rcpf(
            ppd + fmaf(P0.w, a.x, fmaf(P1.w, a.y, fmaf(P2.w, a.z, a.w))));
        aa = fmaf(ra, cwN[k][ka], aa); ab = fmaf(rb, cwN[k][kc], ab);
        ac = fmaf(rc, cwN[k][kd], ac); ad = fmaf(rd, cwN[k][ke], ad);
      }
    }
    inter_l += (aa + ab) + (ac + ad);
    // intra: huber toward own bg-zeroed mean; f_intra folds cf/(3*cnt)
    {
      float4 z = Z_s[ka];
      float q0 = fabsf(P0.x - z.x), q1 = fabsf(P1.x - z.y), q2 = fabsf(P2.x - z.z);
      float hp = (q0 < 1.f ? 0.5f * q0 * q0 : q0 - 0.5f) +
                 (q1 < 1.f ? 0.5f * q1 * q1 : q1 - 0.5f) +
                 (q2 < 1.f ? 0.5f * q2 * q2 : q2 - 0.5f);
      intra_l = fmaf(hp, z.w, intra_l);
    }
    {
      float4 z = Z_s[kc];
      float q0 = fabsf(P0.y - z.x), q1 = fabsf(P1.y - z.y), q2 = fabsf(P2.y - z.z);
      float hp = (q0 < 1.f ? 0.5f * q0 * q0 : q0 - 0.5f) +
                 (q1 < 1.f ? 0.5f * q1 * q1 : q1 - 0.5f) +
                 (q2 < 1.f ? 0.5f * q2 * q2 : q2 - 0.5f);
      intra_l = fmaf(hp, z.w, intra_l);
    }
    {
      float4 z = Z_s[kd];
      float q0 = fabsf(P0.z - z.x), q1 = fabsf(P1.z - z.y), q2 = fabsf(P2.z - z.z);
      float hp = (q0 < 1.f ? 0.5f * q0 * q0 : q0 - 0.5f) +
                 (q1 < 1.f ? 0.5f * q1 * q1 : q1 - 0.5f) +
                 (q2 < 1.f ? 0.5f * q2 * q2 : q2 - 0.5f);
      intra_l = fmaf(hp, z.w, intra_l);
    }
    {
      float4 z = Z_s[ke];
      float q0 = fabsf(P0.w - z.x), q1 = fabsf(P1.w - z.y), q2 = fabsf(P2.w - z.z);
      float hp = (q0 < 1.f ? 0.5f * q0 * q0 : q0 - 0.5f) +
                 (q1 < 1.f ? 0.5f * q1 * q1 : q1 - 0.5f) +
                 (q2 < 1.f ? 0.5f * q2 * q2 : q2 - 0.5f);
      intra_l = fmaf(hp, z.w, intra_l);
    }
  }
  // scalar tail pixels (HW % 4 != 0 only)
  for (int i = (nq << 2) + blockIdx.x * blockDim.x + t; i < HW;
       i += gridDim.x * blockDim.x) {
    float p0 = pb[i], p1 = pb[i + HW], p2 = pb[i + 2 * HW];
    int k0 = USE_CACHE ? (int)k0c[(size_t)b * HW + i]
                       : decode_k0(tb[i], tb[i + HW], tb[i + 2 * HW], pal_s);
    float pp = fmaf(p0, p0, fmaf(p1, p1, p2 * p2));
    float acc = 0.f;
    for (int k = 0; k < KINST; ++k) {
      float4 a = A_s[k];
      float r = __builtin_amdgcn_rcpf(
          pp + fmaf(p0, a.x, fmaf(p1, a.y, fmaf(p2, a.z, a.w))));
      float c = nonuni ? cwN[k][k0]
                       : ((k == k0 || k0 >= KINST) ? 0.f : W_s[k]);
      acc = fmaf(r, c, acc);
    }
    inter_l += acc;
    float4 z = Z_s[k0];
    float q0 = fabsf(p0 - z.x), q1 = fabsf(p1 - z.y), q2 = fabsf(p2 - z.z);
    float hp = (q0 < 1.f ? 0.5f * q0 * q0 : q0 - 0.5f) +
               (q1 < 1.f ? 0.5f * q1 * q1 : q1 - 0.5f) +
               (q2 < 1.f ? 0.5f * q2 * q2 : q2 - 0.5f);
    intra_l = fmaf(hp, z.w, intra_l);
  }
  for (int o = 32; o > 0; o >>= 1) {
    intra_l += __shfl_down(intra_l, o, 64);
    inter_l += __shfl_down(inter_l, o, 64);
  }
  int wid = t >> 6;
  if ((t & 63) == 0) { rA[wid] = intra_l; rB[wid] = inter_l; }
  __syncthreads();
  if (t == 0) {
    float a = 0.f, c = 0.f;
    for (int i = 0; i < 4; ++i) { a += rA[i]; c += rB[i]; }
    float* rp = res_part + ((size_t)b * gridDim.x + blockIdx.x) * 2;
    rp[0] = a; rp[1] = c;  // plain store, no atomics
  }
}

// ---------------------------------------------------------------------------
// Pass 4 (grid=B, light): reduce res_part + combine with msep; atomicAdd.
// ---------------------------------------------------------------------------
__global__ __launch_bounds__(256) void k_final(const float2* __restrict__ msep_g,
                                               const float* __restrict__ res_part,
                                               int ngx,
                                               float* __restrict__ out, int B) {
  int b = blockIdx.x;
  int t = threadIdx.x;
  __shared__ float rD[4], rE[4];
  float ra = 0.f, rc = 0.f;
  for (int bx = t; bx < ngx; bx += blockDim.x) {
    const float* rp = res_part + ((size_t)b * ngx + bx) * 2;
    ra += rp[0]; rc += rp[1];
  }
  for (int o = 32; o > 0; o >>= 1) {
    ra += __shfl_down(ra, o, 64);
    rc += __shfl_down(rc, o, 64);
  }
  int wid = t >> 6;
  if ((t & 63) == 0) { rD[wid] = ra; rE[wid] = rc; }
  __syncthreads();
  if (t == 0) {
    float sa = 0.f, sc2 = 0.f;
    for (int i = 0; i < 4; ++i) { sa += rD[i]; sc2 += rE[i]; }
    float2 ms = msep_g[b];
    atomicAdd(out, ((sa + sc2 + ms.x) / ms.y) / (float)B);
  }
}

extern "C" void kernel_launch(void* const* d_in, const int* in_sizes, int n_in,
                              void* d_out, int out_size, void* d_ws, size_t ws_size,
                              hipStream_t stream) {
  const float* pred = (const float*)d_in[0];
  const float* targ = (const float*)d_in[1];
  const unsigned char* nb = (const unsigned char*)d_in[2];
  const float* dw = (const float*)d_in[3];
  const int* pal = (const int*)d_in[4];
  int B = in_sizes[2];                 // 4
  int ndw = in_sizes[3];               // K*K = 4096
  int HW = in_sizes[0] / (3 * B);      // 262144  (kernels assume K==64)
  const int GX = 256;                  // k_pix blocks per b

  // ws layout (floats): partialS[B*nbs*256] | res_part[B*GX*2] | flagp[B]
  //   | msep[B*2] | A_g | W_g | Z_g | cw_g ; then bytes: k0c[B*HW]
  auto floats_needed = [&](int nbs) -> size_t {
    return (size_t)B * nbs * 256 + (size_t)B * GX * 2 + B + (size_t)B * 2 +
           (size_t)B * 65 * 4 + (size_t)B * 65 + (size_t)B * 65 * 4 +
           (size_t)B * KINST * 65;
  };
  int nbs = 64;
  bool use_cache = true;
  if (ws_size < floats_needed(64) * 4 + (size_t)B * HW) {
    if (ws_size >= floats_needed(32) * 4 + (size_t)B * HW) nbs = 32;
    else { nbs = 32; use_cache = false; }
  }
  float* partialS = (float*)d_ws;
  float* res_part = partialS + (size_t)B * nbs * 256;
  int* flagp = (int*)(res_part + (size_t)B * GX * 2);
  float2* msep_g = (float2*)(flagp + B);
  float4* A_g = (float4*)(msep_g + B);
  float* W_g = (float*)(A_g + (size_t)B * 65);
  float4* Z_g = (float4*)(W_g + (size_t)B * 65);
  float* cw_g = (float*)(Z_g + (size_t)B * 65);
  unsigned char* k0c = use_cache ? (unsigned char*)(cw_g + (size_t)B * KINST * 65)
                                 : nullptr;

  k_stats<<<dim3(nbs, B), 256, 0, stream>>>(pred, targ, pal, partialS, k0c,
                                            (float*)d_out, HW);
  k_reduce<<<B, 256, 0, stream>>>(partialS, dw, pal, nb, ndw, nbs, A_g, W_g,
                                  Z_g, cw_g, flagp, msep_g, B, HW);
  if (use_cache)
    k_pix<true><<<dim3(GX, B), 256, 0, stream>>>(pred, targ, k0c, pal, A_g, W_g,
                                                 Z_g, cw_g, flagp, res_part, HW, B);
  else
    k_pix<false><<<dim3(GX, B), 256, 0, stream>>>(pred, targ, k0c, pal, A_g, W_g,
                                                  Z_g, cw_g, flagp, res_part, HW, B);
  k_final<<<B, 256, 0, stream>>>(msep_g, res_part, GX, (float*)d_out, B);
}